// Round 7
// baseline (314.157 us; speedup 1.0000x reference)
//
#include <hip/hip_runtime.h>
#include <hip/hip_bf16.h>

// LocalWindowedAttention4D on MI355X (gfx950)
// B=2 C=4 S=2048 E=512 H=8 D=64 WIN=256. All-bf16 MFMA pipeline, fp32 accum.
//
// R5 (2nd resubmit; rounds 5+6 both died on infra before measuring):
// R4's fused fp32->bf16 A-staging + XCD panel-locality swizzle: the 4
// column-blocks of each 128-row A-panel map to the SAME XCD (wg%8 equal), so
// the fp32 panel is HBM-fetched once and L2-served 3x. Same swizzle on
// gemm_out. Both GEMMs at 4 wgs/CU.

typedef __bf16 bf16x8 __attribute__((ext_vector_type(8)));
typedef float f32x4 __attribute__((ext_vector_type(4)));
typedef unsigned short u16x8 __attribute__((ext_vector_type(8)));
typedef unsigned int u32x2 __attribute__((ext_vector_type(2)));

#define GLDS(gp, lp) __builtin_amdgcn_global_load_lds( \
    (const __attribute__((address_space(1))) void*)(gp), \
    (__attribute__((address_space(3))) void*)(lp), 16, 0, 0)

__device__ __forceinline__ unsigned short f2bf(float f) {
  unsigned u = __float_as_uint(f);
  return (unsigned short)((u + 0x7fffu + ((u >> 16) & 1u)) >> 16);
}

// ---------------- weight convert (2 MB bf16 out) ----------------
__global__ void convert_w(const float* __restrict__ wq, const float* __restrict__ wk,
                          const float* __restrict__ wv, const float* __restrict__ wo,
                          unsigned short* __restrict__ dwq, unsigned short* __restrict__ dwk,
                          unsigned short* __restrict__ dwv, unsigned short* __restrict__ dwo) {
  int z = blockIdx.z;
  const float* s = z == 0 ? wq : z == 1 ? wk : z == 2 ? wv : wo;
  unsigned short* d = z == 0 ? dwq : z == 1 ? dwk : z == 2 ? dwv : dwo;
  long long i = ((long long)blockIdx.x * 256 + threadIdx.x) * 8;
  f32x4 a = *reinterpret_cast<const f32x4*>(s + i);
  f32x4 b = *reinterpret_cast<const f32x4*>(s + i + 4);
  u16x8 o;
  o[0] = f2bf(a[0]); o[1] = f2bf(a[1]); o[2] = f2bf(a[2]); o[3] = f2bf(a[3]);
  o[4] = f2bf(b[0]); o[5] = f2bf(b[1]); o[6] = f2bf(b[2]); o[7] = f2bf(b[3]);
  *reinterpret_cast<u16x8*>(d + i) = o;
}

// XCD panel swizzle for a (4 col-blocks) x (128 row-panels) grid launched flat:
// all 4 col-blocks of a row-panel share wg%8 -> same XCD -> A-panel L2 reuse.
__device__ __forceinline__ void panel_swizzle(int wg, int& bx, int& by) {
  int xcd = wg & 7, idx = wg >> 3;
  by = xcd + 8 * (idx >> 2);   // row panel 0..127
  bx = idx & 3;                // col block 0..3
}

// ---------------- fused convert+QKV GEMM ----------------
// A (fp32 input) register-staged: thread owns 32 fp32 (row t>>1, kcols
// (t&1)*32..+31), prefetched under the MFMA phase, converted and
// ds_write_b128'd into an XOR-swizzled [128][64] bf16 tile. B (bf16 weights)
// via global_load_lds linear. z=2 stores V transposed [(bc*8+h)*64+d][s].
__global__ __launch_bounds__(256, 4)
void gemm_qkv(const float* __restrict__ Xq, const float* __restrict__ Xk,
              const float* __restrict__ Xv,
              const unsigned short* __restrict__ wq, const unsigned short* __restrict__ wk,
              const unsigned short* __restrict__ wv,
              const float* __restrict__ bq, const float* __restrict__ bk,
              const float* __restrict__ bv,
              unsigned short* __restrict__ qout, unsigned short* __restrict__ kout,
              unsigned short* __restrict__ vtout) {
  __shared__ char lds_raw[33280];  // A 16KB | B 16KB; epilogue reuses as [128][130]
  const int z = blockIdx.z;
  const float* Af          = z == 0 ? Xq : z == 1 ? Xk : Xv;
  const unsigned short* Bw = z == 0 ? wq : z == 1 ? wk : wv;
  const float* bias        = z == 0 ? bq : z == 1 ? bk : bv;

  unsigned short* Blds = (unsigned short*)(lds_raw + 16384);
  const int t = threadIdx.x;
  const int l = t & 63, w = t >> 6;
  const int lrow = l & 15, lk = l >> 4;
  int bx, by;
  panel_swizzle(blockIdx.x, bx, by);
  const int rbase = by * 128, cbase = bx * 128;
  const int wm = w >> 1, wn = w & 1;
  f32x4 acc[4][4] = {};

  const int row2 = t >> 1;          // 0..127: A row this thread stages
  const int kh = (t & 1) * 32;      // fp32 col offset within BK=64
  const float* abase = Af + (size_t)(rbase + row2) * 512 + kh;
  const int wsw = row2 & 7;         // row swizzle key

  f32x4 ar[8];
#pragma unroll
  for (int i = 0; i < 8; ++i) ar[i] = *reinterpret_cast<const f32x4*>(abase + i * 4);

  for (int k0 = 0; k0 < 512; k0 += 64) {
    __syncthreads();
    // A: convert 32 fp32 -> bf16, swizzled ds_write_b128 x4
#pragma unroll
    for (int j = 0; j < 4; ++j) {
      bf16x8 pk;
#pragma unroll
      for (int e = 0; e < 4; ++e) {
        pk[e] = (__bf16)ar[2 * j][e];
        pk[4 + e] = (__bf16)ar[2 * j + 1][e];
      }
      int chunk = (kh >> 3) + j;    // 16B chunk 0..7 within the 128B row
      *reinterpret_cast<bf16x8*>(lds_raw + row2 * 128 + ((chunk ^ wsw) << 4)) = pk;
    }
    // B: global_load_lds (wave-uniform dest), linear
#pragma unroll
    for (int i = 0; i < 4; ++i) {
      int byteoff = w * 4096 + i * 1024;
      int brow = w * 32 + i * 8 + (l >> 3);
      int chunk = l & 7;
      GLDS(Bw + (size_t)(cbase + brow) * 512 + k0 + chunk * 8, lds_raw + 16384 + byteoff);
    }
    __syncthreads();
    // prefetch next A-subtile; latency hides under the MFMA phase below
    if (k0 + 64 < 512) {
#pragma unroll
      for (int i = 0; i < 8; ++i)
        ar[i] = *reinterpret_cast<const f32x4*>(abase + (k0 + 64) + i * 4);
    }

    bf16x8 af[4][2], bfr[4][2];
#pragma unroll
    for (int mt = 0; mt < 4; ++mt)
#pragma unroll
      for (int ks = 0; ks < 2; ++ks) {
        int arow = wm * 64 + mt * 16 + lrow;
        af[mt][ks] = *reinterpret_cast<const bf16x8*>(
            lds_raw + arow * 128 + (((ks * 4 + lk) ^ (arow & 7)) << 4));
        bfr[mt][ks] = *reinterpret_cast<const bf16x8*>(
            Blds + (wn * 64 + mt * 16 + lrow) * 64 + ks * 32 + lk * 8);
      }
#pragma unroll
    for (int mt = 0; mt < 4; ++mt)
#pragma unroll
      for (int nt = 0; nt < 4; ++nt) {
        acc[mt][nt] = __builtin_amdgcn_mfma_f32_16x16x32_bf16(af[mt][0], bfr[nt][0], acc[mt][nt], 0, 0, 0);
        acc[mt][nt] = __builtin_amdgcn_mfma_f32_16x16x32_bf16(af[mt][1], bfr[nt][1], acc[mt][nt], 0, 0, 0);
      }
  }

  float bvv[4];
#pragma unroll
  for (int nt = 0; nt < 4; ++nt) bvv[nt] = bias[cbase + wn * 64 + nt * 16 + lrow];

  if (z < 2) {
    unsigned short* out = z == 0 ? qout : kout;
#pragma unroll
    for (int mt = 0; mt < 4; ++mt)
#pragma unroll
      for (int nt = 0; nt < 4; ++nt)
#pragma unroll
        for (int r = 0; r < 4; ++r) {
          int rg = rbase + wm * 64 + mt * 16 + lk * 4 + r;
          int cg = cbase + wn * 64 + nt * 16 + lrow;
          out[(size_t)rg * 512 + cg] = f2bf(acc[mt][nt][r] + bvv[nt]);
        }
  } else {
    __syncthreads();
    unsigned short* tl = (unsigned short*)lds_raw;  // [128][130]
#pragma unroll
    for (int mt = 0; mt < 4; ++mt)
#pragma unroll
      for (int nt = 0; nt < 4; ++nt)
#pragma unroll
        for (int r = 0; r < 4; ++r)
          tl[(wm * 64 + mt * 16 + lk * 4 + r) * 130 + wn * 64 + nt * 16 + lrow] =
              f2bf(acc[mt][nt][r] + bvv[nt]);
    __syncthreads();
    const int bc = rbase >> 11;
    const int sb = rbase & 2047;
#pragma unroll
    for (int rnd = 0; rnd < 8; ++rnd) {
      int idx = rnd * 256 + t;
      int el = idx >> 4;
      int ch = idx & 15;
      u16x8 pk;
#pragma unroll
      for (int j2 = 0; j2 < 8; ++j2) pk[j2] = tl[(ch * 8 + j2) * 130 + el];
      int eg = cbase + el;
      int hh = eg >> 6, dd = eg & 63;
      *reinterpret_cast<u16x8*>(vtout + ((size_t)(bc * 8 + hh) * 64 + dd) * 2048 + sb + ch * 8) = pk;
    }
  }
}

// ---------------- output GEMM (fp32 out), same panel swizzle ----------------
__global__ __launch_bounds__(256, 4)
void gemm_out(const unsigned short* __restrict__ A, const unsigned short* __restrict__ Bw,
              const float* __restrict__ bias, float* __restrict__ out) {
  __shared__ char lds_raw[32768];
  unsigned short* Alds = (unsigned short*)lds_raw;
  unsigned short* Blds = (unsigned short*)(lds_raw + 16384);
  const int t = threadIdx.x;
  const int l = t & 63, w = t >> 6;
  const int lrow = l & 15, lk = l >> 4;
  int bx, by;
  panel_swizzle(blockIdx.x, bx, by);
  const int rbase = by * 128, cbase = bx * 128;
  const int wm = w >> 1, wn = w & 1;
  f32x4 acc[4][4] = {};

  for (int k0 = 0; k0 < 512; k0 += 64) {
    __syncthreads();
#pragma unroll
    for (int i = 0; i < 4; ++i) {
      int byteoff = w * 4096 + i * 1024;
      int row = w * 32 + i * 8 + (l >> 3);
      int chunk = l & 7;
      GLDS(A + (size_t)(rbase + row) * 512 + k0 + chunk * 8, lds_raw + byteoff);
      GLDS(Bw + (size_t)(cbase + row) * 512 + k0 + chunk * 8, lds_raw + 16384 + byteoff);
    }
    __syncthreads();
    bf16x8 af[4][2], bfr[4][2];
#pragma unroll
    for (int mt = 0; mt < 4; ++mt)
#pragma unroll
      for (int ks = 0; ks < 2; ++ks) {
        af[mt][ks]  = *reinterpret_cast<const bf16x8*>(Alds + (wm * 64 + mt * 16 + lrow) * 64 + ks * 32 + lk * 8);
        bfr[mt][ks] = *reinterpret_cast<const bf16x8*>(Blds + (wn * 64 + mt * 16 + lrow) * 64 + ks * 32 + lk * 8);
      }
#pragma unroll
    for (int mt = 0; mt < 4; ++mt)
#pragma unroll
      for (int nt = 0; nt < 4; ++nt) {
        acc[mt][nt] = __builtin_amdgcn_mfma_f32_16x16x32_bf16(af[mt][0], bfr[nt][0], acc[mt][nt], 0, 0, 0);
        acc[mt][nt] = __builtin_amdgcn_mfma_f32_16x16x32_bf16(af[mt][1], bfr[nt][1], acc[mt][nt], 0, 0, 0);
      }
  }

  float bvv[4];
#pragma unroll
  for (int nt = 0; nt < 4; ++nt) bvv[nt] = bias[cbase + wn * 64 + nt * 16 + lrow];
#pragma unroll
  for (int mt = 0; mt < 4; ++mt)
#pragma unroll
    for (int nt = 0; nt < 4; ++nt)
#pragma unroll
      for (int r = 0; r < 4; ++r) {
        int rg = rbase + wm * 64 + mt * 16 + lk * 4 + r;
        int cg = cbase + wn * 64 + nt * 16 + lrow;
        out[(size_t)rg * 512 + cg] = acc[mt][nt][r] + bvv[nt];
      }
}

// ---------------- fused windowed attention (R3 structure, unchanged) ----------------
__global__ __launch_bounds__(256, 4)
void attn_kernel(const unsigned short* __restrict__ qm, const unsigned short* __restrict__ km,
                 const unsigned short* __restrict__ vtm, unsigned short* __restrict__ ctx) {
  __shared__ char lds_raw[40960];  // 2 x (K 8KB | V^T 8KB) | P: 4 waves x 2KB
  const int t = threadIdx.x, l = t & 63, w = t >> 6;
  char* Pl = lds_raw + 32768 + w * 2048;
  const int lm = l & 15, g = l >> 4;

  int flat = blockIdx.x;
  int swz = (flat & 7) * 128 + (flat >> 3);   // nwg=1024, bijective XCD swizzle
  const int jh = swz & 15, h = (swz >> 4) & 7, bc = swz >> 7;

  const int Qb = jh * 128;
  const int qlo = Qb + w * 32;
  const int h64 = h * 64;
  const size_t bcrow = (size_t)bc * 2048;
  const size_t bch64 = ((size_t)(bc * 8 + h)) * 64;

  const int tlo = (Qb > 255 ? Qb - 255 : 0) >> 6;
  const int thi = (Qb + 127) >> 6;
  const int nt = thi - tlo + 1;
  const int wlo = (qlo > 255 ? qlo - 255 : 0) >> 6;
  const int whi = (qlo + 31) >> 6;

  auto stage = [&](int tt, int buf) {
    char* Kb = lds_raw + buf * 16384;
#pragma unroll
    for (int i = 0; i < 2; ++i) {
      int byteoff = w * 2048 + i * 1024;
      int row = w * 16 + i * 8 + (l >> 3);
      int clog = (l & 7) ^ (row & 7);            // pre-swizzled source (rule #21)
      GLDS(km + (bcrow + tt * 64 + row) * 512 + h64 + clog * 8, Kb + byteoff);
      GLDS(vtm + (bch64 + row) * 2048 + tt * 64 + clog * 8, Kb + 8192 + byteoff);
    }
  };

  bf16x8 qf[2][2];
#pragma unroll
  for (int rt = 0; rt < 2; ++rt)
#pragma unroll
    for (int ks = 0; ks < 2; ++ks)
      qf[rt][ks] = *reinterpret_cast<const bf16x8*>(
          qm + (bcrow + qlo + rt * 16 + lm) * 512 + h64 + ks * 32 + g * 8);

  f32x4 oacc[2][4] = {};
  float ls[2] = {0.f, 0.f};

  stage(tlo, 0);
  __syncthreads();

  for (int it = 0; it < nt; ++it) {
    const int tt = tlo + it;
    if (it + 1 < nt) stage(tt + 1, (it + 1) & 1);

    if (tt >= wlo && tt <= whi) {
      char* Kb = lds_raw + (it & 1) * 16384;
      char* Vb = Kb + 8192;

      f32x4 sc[2][4];
      f32x4 zero = {};
#pragma unroll
      for (int kt = 0; kt < 4; ++kt) {
        int krow = kt * 16 + lm;
        const char* kbase = Kb + krow * 128;
        bf16x8 kf0 = *reinterpret_cast<const bf16x8*>(kbase + ((g ^ (krow & 7)) << 4));
        bf16x8 kf1 = *reinterpret_cast<const bf16x8*>(kbase + (((4 + g) ^ (krow & 7)) << 4));
#pragma unroll
        for (int rt = 0; rt < 2; ++rt) {
          f32x4 s0 = __builtin_amdgcn_mfma_f32_16x16x32_bf16(kf0, qf[rt][0], zero, 0, 0, 0);
          sc[rt][kt] = __builtin_amdgcn_mfma_f32_16x16x32_bf16(kf1, qf[rt][1], s0, 0, 0, 0);
        }
      }

      const bool interior = (tt * 64 + 63 <= qlo) && (tt * 64 >= qlo + 31 - 255);
      if (interior) {
#pragma unroll
        for (int rt = 0; rt < 2; ++rt) {
          float acc = 0.f;
#pragma unroll
          for (int kt = 0; kt < 4; ++kt)
#pragma unroll
            for (int r = 0; r < 4; ++r) {
              float pv = __expf(sc[rt][kt][r] * 0.125f);
              sc[rt][kt][r] = pv;
              acc += pv;
            }
          ls[rt] += acc;
        }
      } else {
#pragma unroll
        for (int rt = 0; rt < 2; ++rt) {
          int d0 = qlo + rt * 16 + lm - (tt * 64 + g * 4);
          float acc = 0.f;
#pragma unroll
          for (int kt = 0; kt < 4; ++kt)
#pragma unroll
            for (int r = 0; r < 4; ++r) {
              bool ok = (unsigned)(d0 - (kt * 16 + r)) <= 255u;
              float pv = ok ? __expf(sc[rt][kt][r] * 0.125f) : 0.f;
              sc[rt][kt][r] = pv;
              acc += pv;
            }
          ls[rt] += acc;
        }
      }

#pragma unroll
      for (int ks = 0; ks < 2; ++ks) {
#pragma unroll
        for (int rt = 0; rt < 2; ++rt)
#pragma unroll
          for (int ktl = 0; ktl < 2; ++ktl) {
            int kt = ks * 2 + ktl;
            unsigned u0, u1;
            asm("v_cvt_pk_bf16_f32 %0, %1, %2" : "=v"(u0) : "v"(sc[rt][kt][0]), "v"(sc[rt][kt][1]));
            asm("v_cvt_pk_bf16_f32 %0, %1, %2" : "=v"(u1) : "v"(sc[rt][kt][2]), "v"(sc[rt][kt][3]));
            u32x2 uu; uu[0] = u0; uu[1] = u1;
            *reinterpret_cast<u32x2*>(Pl + (rt * 16 + lm) * 64 + ktl * 32 + g * 8) = uu;
          }
        bf16x8 pa[2];
        pa[0] = *reinterpret_cast<const bf16x8*>(Pl + lm * 64 + g * 16);
        pa[1] = *reinterpret_cast<const bf16x8*>(Pl + (16 + lm) * 64 + g * 16);
        bf16x8 vb[4];
#pragma unroll
        for (int dt = 0; dt < 4; ++dt) {
          int vrow = dt * 16 + lm;
          vb[dt] = *reinterpret_cast<const bf16x8*>(Vb + vrow * 128 + (((ks * 4 + g) ^ (vrow & 7)) << 4));
        }
#pragma unroll
        for (int rt = 0; rt < 2; ++rt)
#pragma unroll
          for (int dt = 0; dt < 4; ++dt)
            oacc[rt][dt] = __builtin_amdgcn_mfma_f32_16x16x32_bf16(pa[rt], vb[dt], oacc[rt][dt], 0, 0, 0);
      }
    }
    __syncthreads();
  }

#pragma unroll
  for (int rt = 0; rt < 2; ++rt) {
    ls[rt] += __shfl_xor(ls[rt], 16, 64);
    ls[rt] += __shfl_xor(ls[rt], 32, 64);
    int cp = 255 - (qlo + rt * 16 + lm);
    if (cp > 0) ls[rt] += (float)cp;
  }

  float* Pf = (float*)Pl;
  Pf[lm] = 1.f / ls[0];
  Pf[16 + lm] = 1.f / ls[1];
  float inv0[2][4];
#pragma unroll
  for (int rt = 0; rt < 2; ++rt)
#pragma unroll
    for (int r = 0; r < 4; ++r)
      inv0[rt][r] = Pf[rt * 16 + g * 4 + r];

#pragma unroll
  for (int rt = 0; rt < 2; ++rt)
#pragma unroll
    for (int dt = 0; dt < 4; ++dt)
#pragma unroll
      for (int r = 0; r < 4; ++r) {
        size_t rg = bcrow + qlo + rt * 16 + g * 4 + r;
        int cg = h64 + dt * 16 + lm;
        ctx[rg * 512 + cg] = f2bf(oacc[rt][dt][r] * inv0[rt][r]);
      }
}

// ---------------- launch ----------------
extern "C" void kernel_launch(void* const* d_in, const int* in_sizes, int n_in,
                              void* d_out, int out_size, void* d_ws, size_t ws_size,
                              hipStream_t stream) {
  const float* q_in = (const float*)d_in[0];
  const float* k_in = (const float*)d_in[1];
  const float* v_in = (const float*)d_in[2];
  const float* Wq = (const float*)d_in[3];
  const float* bq = (const float*)d_in[4];
  const float* Wk = (const float*)d_in[5];
  const float* bk = (const float*)d_in[6];
  const float* Wv = (const float*)d_in[7];
  const float* bv = (const float*)d_in[8];
  const float* Wo = (const float*)d_in[9];
  const float* bo = (const float*)d_in[10];

  char* ws = (char*)d_ws;
  const size_t SZ = (size_t)16384 * 512 * 2;
  unsigned short* qb = (unsigned short*)(ws + 3 * SZ);
  unsigned short* kb = (unsigned short*)(ws + 4 * SZ);
  unsigned short* wq_b = (unsigned short*)(ws + 5 * SZ);
  unsigned short* wk_b = wq_b + 262144;
  unsigned short* wv_b = wk_b + 262144;
  unsigned short* wo_b = wv_b + 262144;
  unsigned short* vtb = (unsigned short*)d_out;  // vT in d_out (dead before gemm_out)
  unsigned short* ctx = (unsigned short*)ws;     // ws[0] free

  convert_w<<<dim3(128, 1, 4), 256, 0, stream>>>(Wq, Wk, Wv, Wo, wq_b, wk_b, wv_b, wo_b);
  gemm_qkv<<<dim3(512, 1, 3), 256, 0, stream>>>(q_in, k_in, v_in, wq_b, wk_b, wv_b,
                                                bq, bk, bv, qb, kb, vtb);
  attn_kernel<<<1024, 256, 0, stream>>>(qb, kb, vtb, ctx);
  gemm_out<<<dim3(512, 1), 256, 0, stream>>>(ctx, wo_b, bo, (float*)d_out);
}

// Round 8
// 257.198 us; speedup vs baseline: 1.2215x; 1.2215x over previous
//
#include <hip/hip_runtime.h>
#include <hip/hip_bf16.h>

// LocalWindowedAttention4D on MI355X (gfx950)
// B=2 C=4 S=2048 E=512 H=8 D=64 WIN=256. All-bf16 MFMA pipeline, fp32 accum.
//
// R8: R7 minus the spill regression. R7's launch_bounds(256,4) forced VGPR
// 84->64 -> scratch spills (WRITE 49->198MB). Revert to (256,3); keep the
// XCD panel swizzle (verified: FETCH 199->117MB) and fused fp32->bf16 A-staging.

typedef __bf16 bf16x8 __attribute__((ext_vector_type(8)));
typedef float f32x4 __attribute__((ext_vector_type(4)));
typedef unsigned short u16x8 __attribute__((ext_vector_type(8)));
typedef unsigned int u32x2 __attribute__((ext_vector_type(2)));

#define GLDS(gp, lp) __builtin_amdgcn_global_load_lds( \
    (const __attribute__((address_space(1))) void*)(gp), \
    (__attribute__((address_space(3))) void*)(lp), 16, 0, 0)

__device__ __forceinline__ unsigned short f2bf(float f) {
  unsigned u = __float_as_uint(f);
  return (unsigned short)((u + 0x7fffu + ((u >> 16) & 1u)) >> 16);
}

// ---------------- weight convert (2 MB bf16 out) ----------------
__global__ void convert_w(const float* __restrict__ wq, const float* __restrict__ wk,
                          const float* __restrict__ wv, const float* __restrict__ wo,
                          unsigned short* __restrict__ dwq, unsigned short* __restrict__ dwk,
                          unsigned short* __restrict__ dwv, unsigned short* __restrict__ dwo) {
  int z = blockIdx.z;
  const float* s = z == 0 ? wq : z == 1 ? wk : z == 2 ? wv : wo;
  unsigned short* d = z == 0 ? dwq : z == 1 ? dwk : z == 2 ? dwv : dwo;
  long long i = ((long long)blockIdx.x * 256 + threadIdx.x) * 8;
  f32x4 a = *reinterpret_cast<const f32x4*>(s + i);
  f32x4 b = *reinterpret_cast<const f32x4*>(s + i + 4);
  u16x8 o;
  o[0] = f2bf(a[0]); o[1] = f2bf(a[1]); o[2] = f2bf(a[2]); o[3] = f2bf(a[3]);
  o[4] = f2bf(b[0]); o[5] = f2bf(b[1]); o[6] = f2bf(b[2]); o[7] = f2bf(b[3]);
  *reinterpret_cast<u16x8*>(d + i) = o;
}

// XCD panel swizzle for a (4 col-blocks) x (128 row-panels) grid launched flat:
// all 4 col-blocks of a row-panel share wg%8 -> same XCD -> A-panel L2 reuse.
__device__ __forceinline__ void panel_swizzle(int wg, int& bx, int& by) {
  int xcd = wg & 7, idx = wg >> 3;
  by = xcd + 8 * (idx >> 2);   // row panel 0..127
  bx = idx & 3;                // col block 0..3
}

// ---------------- fused convert+QKV GEMM ----------------
// A (fp32 input) register-staged: thread owns 32 fp32 (row t>>1, kcols
// (t&1)*32..+31), prefetched under the MFMA phase, converted and
// ds_write_b128'd into an XOR-swizzled [128][64] bf16 tile. B (bf16 weights)
// via global_load_lds linear. z=2 stores V transposed [(bc*8+h)*64+d][s].
// launch_bounds(256,3): VGPR ~84, no spill (R7's (256,4) spilled at VGPR 64).
__global__ __launch_bounds__(256, 3)
void gemm_qkv(const float* __restrict__ Xq, const float* __restrict__ Xk,
              const float* __restrict__ Xv,
              const unsigned short* __restrict__ wq, const unsigned short* __restrict__ wk,
              const unsigned short* __restrict__ wv,
              const float* __restrict__ bq, const float* __restrict__ bk,
              const float* __restrict__ bv,
              unsigned short* __restrict__ qout, unsigned short* __restrict__ kout,
              unsigned short* __restrict__ vtout) {
  __shared__ char lds_raw[33280];  // A 16KB | B 16KB; epilogue reuses as [128][130]
  const int z = blockIdx.z;
  const float* Af          = z == 0 ? Xq : z == 1 ? Xk : Xv;
  const unsigned short* Bw = z == 0 ? wq : z == 1 ? wk : wv;
  const float* bias        = z == 0 ? bq : z == 1 ? bk : bv;

  unsigned short* Blds = (unsigned short*)(lds_raw + 16384);
  const int t = threadIdx.x;
  const int l = t & 63, w = t >> 6;
  const int lrow = l & 15, lk = l >> 4;
  int bx, by;
  panel_swizzle(blockIdx.x, bx, by);
  const int rbase = by * 128, cbase = bx * 128;
  const int wm = w >> 1, wn = w & 1;
  f32x4 acc[4][4] = {};

  const int row2 = t >> 1;          // 0..127: A row this thread stages
  const int kh = (t & 1) * 32;      // fp32 col offset within BK=64
  const float* abase = Af + (size_t)(rbase + row2) * 512 + kh;
  const int wsw = row2 & 7;         // row swizzle key

  f32x4 ar[8];
#pragma unroll
  for (int i = 0; i < 8; ++i) ar[i] = *reinterpret_cast<const f32x4*>(abase + i * 4);

  for (int k0 = 0; k0 < 512; k0 += 64) {
    __syncthreads();
    // A: convert 32 fp32 -> bf16, swizzled ds_write_b128 x4
#pragma unroll
    for (int j = 0; j < 4; ++j) {
      bf16x8 pk;
#pragma unroll
      for (int e = 0; e < 4; ++e) {
        pk[e] = (__bf16)ar[2 * j][e];
        pk[4 + e] = (__bf16)ar[2 * j + 1][e];
      }
      int chunk = (kh >> 3) + j;    // 16B chunk 0..7 within the 128B row
      *reinterpret_cast<bf16x8*>(lds_raw + row2 * 128 + ((chunk ^ wsw) << 4)) = pk;
    }
    // B: global_load_lds (wave-uniform dest), linear
#pragma unroll
    for (int i = 0; i < 4; ++i) {
      int byteoff = w * 4096 + i * 1024;
      int brow = w * 32 + i * 8 + (l >> 3);
      int chunk = l & 7;
      GLDS(Bw + (size_t)(cbase + brow) * 512 + k0 + chunk * 8, lds_raw + 16384 + byteoff);
    }
    __syncthreads();
    // prefetch next A-subtile; latency hides under the MFMA phase below
    if (k0 + 64 < 512) {
#pragma unroll
      for (int i = 0; i < 8; ++i)
        ar[i] = *reinterpret_cast<const f32x4*>(abase + (k0 + 64) + i * 4);
    }

    bf16x8 af[4][2], bfr[4][2];
#pragma unroll
    for (int mt = 0; mt < 4; ++mt)
#pragma unroll
      for (int ks = 0; ks < 2; ++ks) {
        int arow = wm * 64 + mt * 16 + lrow;
        af[mt][ks] = *reinterpret_cast<const bf16x8*>(
            lds_raw + arow * 128 + (((ks * 4 + lk) ^ (arow & 7)) << 4));
        bfr[mt][ks] = *reinterpret_cast<const bf16x8*>(
            Blds + (wn * 64 + mt * 16 + lrow) * 64 + ks * 32 + lk * 8);
      }
#pragma unroll
    for (int mt = 0; mt < 4; ++mt)
#pragma unroll
      for (int nt = 0; nt < 4; ++nt) {
        acc[mt][nt] = __builtin_amdgcn_mfma_f32_16x16x32_bf16(af[mt][0], bfr[nt][0], acc[mt][nt], 0, 0, 0);
        acc[mt][nt] = __builtin_amdgcn_mfma_f32_16x16x32_bf16(af[mt][1], bfr[nt][1], acc[mt][nt], 0, 0, 0);
      }
  }

  float bvv[4];
#pragma unroll
  for (int nt = 0; nt < 4; ++nt) bvv[nt] = bias[cbase + wn * 64 + nt * 16 + lrow];

  if (z < 2) {
    unsigned short* out = z == 0 ? qout : kout;
#pragma unroll
    for (int mt = 0; mt < 4; ++mt)
#pragma unroll
      for (int nt = 0; nt < 4; ++nt)
#pragma unroll
        for (int r = 0; r < 4; ++r) {
          int rg = rbase + wm * 64 + mt * 16 + lk * 4 + r;
          int cg = cbase + wn * 64 + nt * 16 + lrow;
          out[(size_t)rg * 512 + cg] = f2bf(acc[mt][nt][r] + bvv[nt]);
        }
  } else {
    __syncthreads();
    unsigned short* tl = (unsigned short*)lds_raw;  // [128][130]
#pragma unroll
    for (int mt = 0; mt < 4; ++mt)
#pragma unroll
      for (int nt = 0; nt < 4; ++nt)
#pragma unroll
        for (int r = 0; r < 4; ++r)
          tl[(wm * 64 + mt * 16 + lk * 4 + r) * 130 + wn * 64 + nt * 16 + lrow] =
              f2bf(acc[mt][nt][r] + bvv[nt]);
    __syncthreads();
    const int bc = rbase >> 11;
    const int sb = rbase & 2047;
#pragma unroll
    for (int rnd = 0; rnd < 8; ++rnd) {
      int idx = rnd * 256 + t;
      int el = idx >> 4;
      int ch = idx & 15;
      u16x8 pk;
#pragma unroll
      for (int j2 = 0; j2 < 8; ++j2) pk[j2] = tl[(ch * 8 + j2) * 130 + el];
      int eg = cbase + el;
      int hh = eg >> 6, dd = eg & 63;
      *reinterpret_cast<u16x8*>(vtout + ((size_t)(bc * 8 + hh) * 64 + dd) * 2048 + sb + ch * 8) = pk;
    }
  }
}

// ---------------- output GEMM (fp32 out), same panel swizzle ----------------
__global__ __launch_bounds__(256, 3)
void gemm_out(const unsigned short* __restrict__ A, const unsigned short* __restrict__ Bw,
              const float* __restrict__ bias, float* __restrict__ out) {
  __shared__ char lds_raw[32768];
  unsigned short* Alds = (unsigned short*)lds_raw;
  unsigned short* Blds = (unsigned short*)(lds_raw + 16384);
  const int t = threadIdx.x;
  const int l = t & 63, w = t >> 6;
  const int lrow = l & 15, lk = l >> 4;
  int bx, by;
  panel_swizzle(blockIdx.x, bx, by);
  const int rbase = by * 128, cbase = bx * 128;
  const int wm = w >> 1, wn = w & 1;
  f32x4 acc[4][4] = {};

  for (int k0 = 0; k0 < 512; k0 += 64) {
    __syncthreads();
#pragma unroll
    for (int i = 0; i < 4; ++i) {
      int byteoff = w * 4096 + i * 1024;
      int row = w * 32 + i * 8 + (l >> 3);
      int chunk = l & 7;
      GLDS(A + (size_t)(rbase + row) * 512 + k0 + chunk * 8, lds_raw + byteoff);
      GLDS(Bw + (size_t)(cbase + row) * 512 + k0 + chunk * 8, lds_raw + 16384 + byteoff);
    }
    __syncthreads();
    bf16x8 af[4][2], bfr[4][2];
#pragma unroll
    for (int mt = 0; mt < 4; ++mt)
#pragma unroll
      for (int ks = 0; ks < 2; ++ks) {
        af[mt][ks]  = *reinterpret_cast<const bf16x8*>(Alds + (wm * 64 + mt * 16 + lrow) * 64 + ks * 32 + lk * 8);
        bfr[mt][ks] = *reinterpret_cast<const bf16x8*>(Blds + (wn * 64 + mt * 16 + lrow) * 64 + ks * 32 + lk * 8);
      }
#pragma unroll
    for (int mt = 0; mt < 4; ++mt)
#pragma unroll
      for (int nt = 0; nt < 4; ++nt) {
        acc[mt][nt] = __builtin_amdgcn_mfma_f32_16x16x32_bf16(af[mt][0], bfr[nt][0], acc[mt][nt], 0, 0, 0);
        acc[mt][nt] = __builtin_amdgcn_mfma_f32_16x16x32_bf16(af[mt][1], bfr[nt][1], acc[mt][nt], 0, 0, 0);
      }
  }

  float bvv[4];
#pragma unroll
  for (int nt = 0; nt < 4; ++nt) bvv[nt] = bias[cbase + wn * 64 + nt * 16 + lrow];
#pragma unroll
  for (int mt = 0; mt < 4; ++mt)
#pragma unroll
    for (int nt = 0; nt < 4; ++nt)
#pragma unroll
      for (int r = 0; r < 4; ++r) {
        int rg = rbase + wm * 64 + mt * 16 + lk * 4 + r;
        int cg = cbase + wn * 64 + nt * 16 + lrow;
        out[(size_t)rg * 512 + cg] = acc[mt][nt][r] + bvv[nt];
      }
}

// ---------------- fused windowed attention (R3 structure, unchanged) ----------------
__global__ __launch_bounds__(256, 4)
void attn_kernel(const unsigned short* __restrict__ qm, const unsigned short* __restrict__ km,
                 const unsigned short* __restrict__ vtm, unsigned short* __restrict__ ctx) {
  __shared__ char lds_raw[40960];  // 2 x (K 8KB | V^T 8KB) | P: 4 waves x 2KB
  const int t = threadIdx.x, l = t & 63, w = t >> 6;
  char* Pl = lds_raw + 32768 + w * 2048;
  const int lm = l & 15, g = l >> 4;

  int flat = blockIdx.x;
  int swz = (flat & 7) * 128 + (flat >> 3);   // nwg=1024, bijective XCD swizzle
  const int jh = swz & 15, h = (swz >> 4) & 7, bc = swz >> 7;

  const int Qb = jh * 128;
  const int qlo = Qb + w * 32;
  const int h64 = h * 64;
  const size_t bcrow = (size_t)bc * 2048;
  const size_t bch64 = ((size_t)(bc * 8 + h)) * 64;

  const int tlo = (Qb > 255 ? Qb - 255 : 0) >> 6;
  const int thi = (Qb + 127) >> 6;
  const int nt = thi - tlo + 1;
  const int wlo = (qlo > 255 ? qlo - 255 : 0) >> 6;
  const int whi = (qlo + 31) >> 6;

  auto stage = [&](int tt, int buf) {
    char* Kb = lds_raw + buf * 16384;
#pragma unroll
    for (int i = 0; i < 2; ++i) {
      int byteoff = w * 2048 + i * 1024;
      int row = w * 16 + i * 8 + (l >> 3);
      int clog = (l & 7) ^ (row & 7);            // pre-swizzled source (rule #21)
      GLDS(km + (bcrow + tt * 64 + row) * 512 + h64 + clog * 8, Kb + byteoff);
      GLDS(vtm + (bch64 + row) * 2048 + tt * 64 + clog * 8, Kb + 8192 + byteoff);
    }
  };

  bf16x8 qf[2][2];
#pragma unroll
  for (int rt = 0; rt < 2; ++rt)
#pragma unroll
    for (int ks = 0; ks < 2; ++ks)
      qf[rt][ks] = *reinterpret_cast<const bf16x8*>(
          qm + (bcrow + qlo + rt * 16 + lm) * 512 + h64 + ks * 32 + g * 8);

  f32x4 oacc[2][4] = {};
  float ls[2] = {0.f, 0.f};

  stage(tlo, 0);
  __syncthreads();

  for (int it = 0; it < nt; ++it) {
    const int tt = tlo + it;
    if (it + 1 < nt) stage(tt + 1, (it + 1) & 1);

    if (tt >= wlo && tt <= whi) {
      char* Kb = lds_raw + (it & 1) * 16384;
      char* Vb = Kb + 8192;

      f32x4 sc[2][4];
      f32x4 zero = {};
#pragma unroll
      for (int kt = 0; kt < 4; ++kt) {
        int krow = kt * 16 + lm;
        const char* kbase = Kb + krow * 128;
        bf16x8 kf0 = *reinterpret_cast<const bf16x8*>(kbase + ((g ^ (krow & 7)) << 4));
        bf16x8 kf1 = *reinterpret_cast<const bf16x8*>(kbase + (((4 + g) ^ (krow & 7)) << 4));
#pragma unroll
        for (int rt = 0; rt < 2; ++rt) {
          f32x4 s0 = __builtin_amdgcn_mfma_f32_16x16x32_bf16(kf0, qf[rt][0], zero, 0, 0, 0);
          sc[rt][kt] = __builtin_amdgcn_mfma_f32_16x16x32_bf16(kf1, qf[rt][1], s0, 0, 0, 0);
        }
      }

      const bool interior = (tt * 64 + 63 <= qlo) && (tt * 64 >= qlo + 31 - 255);
      if (interior) {
#pragma unroll
        for (int rt = 0; rt < 2; ++rt) {
          float acc = 0.f;
#pragma unroll
          for (int kt = 0; kt < 4; ++kt)
#pragma unroll
            for (int r = 0; r < 4; ++r) {
              float pv = __expf(sc[rt][kt][r] * 0.125f);
              sc[rt][kt][r] = pv;
              acc += pv;
            }
          ls[rt] += acc;
        }
      } else {
#pragma unroll
        for (int rt = 0; rt < 2; ++rt) {
          int d0 = qlo + rt * 16 + lm - (tt * 64 + g * 4);
          float acc = 0.f;
#pragma unroll
          for (int kt = 0; kt < 4; ++kt)
#pragma unroll
            for (int r = 0; r < 4; ++r) {
              bool ok = (unsigned)(d0 - (kt * 16 + r)) <= 255u;
              float pv = ok ? __expf(sc[rt][kt][r] * 0.125f) : 0.f;
              sc[rt][kt][r] = pv;
              acc += pv;
            }
          ls[rt] += acc;
        }
      }

#pragma unroll
      for (int ks = 0; ks < 2; ++ks) {
#pragma unroll
        for (int rt = 0; rt < 2; ++rt)
#pragma unroll
          for (int ktl = 0; ktl < 2; ++ktl) {
            int kt = ks * 2 + ktl;
            unsigned u0, u1;
            asm("v_cvt_pk_bf16_f32 %0, %1, %2" : "=v"(u0) : "v"(sc[rt][kt][0]), "v"(sc[rt][kt][1]));
            asm("v_cvt_pk_bf16_f32 %0, %1, %2" : "=v"(u1) : "v"(sc[rt][kt][2]), "v"(sc[rt][kt][3]));
            u32x2 uu; uu[0] = u0; uu[1] = u1;
            *reinterpret_cast<u32x2*>(Pl + (rt * 16 + lm) * 64 + ktl * 32 + g * 8) = uu;
          }
        bf16x8 pa[2];
        pa[0] = *reinterpret_cast<const bf16x8*>(Pl + lm * 64 + g * 16);
        pa[1] = *reinterpret_cast<const bf16x8*>(Pl + (16 + lm) * 64 + g * 16);
        bf16x8 vb[4];
#pragma unroll
        for (int dt = 0; dt < 4; ++dt) {
          int vrow = dt * 16 + lm;
          vb[dt] = *reinterpret_cast<const bf16x8*>(Vb + vrow * 128 + (((ks * 4 + g) ^ (vrow & 7)) << 4));
        }
#pragma unroll
        for (int rt = 0; rt < 2; ++rt)
#pragma unroll
          for (int dt = 0; dt < 4; ++dt)
            oacc[rt][dt] = __builtin_amdgcn_mfma_f32_16x16x32_bf16(pa[rt], vb[dt], oacc[rt][dt], 0, 0, 0);
      }
    }
    __syncthreads();
  }

#pragma unroll
  for (int rt = 0; rt < 2; ++rt) {
    ls[rt] += __shfl_xor(ls[rt], 16, 64);
    ls[rt] += __shfl_xor(ls[rt], 32, 64);
    int cp = 255 - (qlo + rt * 16 + lm);
    if (cp > 0) ls[rt] += (float)cp;
  }

  float* Pf = (float*)Pl;
  Pf[lm] = 1.f / ls[0];
  Pf[16 + lm] = 1.f / ls[1];
  float inv0[2][4];
#pragma unroll
  for (int rt = 0; rt < 2; ++rt)
#pragma unroll
    for (int r = 0; r < 4; ++r)
      inv0[rt][r] = Pf[rt * 16 + g * 4 + r];

#pragma unroll
  for (int rt = 0; rt < 2; ++rt)
#pragma unroll
    for (int dt = 0; dt < 4; ++dt)
#pragma unroll
      for (int r = 0; r < 4; ++r) {
        size_t rg = bcrow + qlo + rt * 16 + g * 4 + r;
        int cg = h64 + dt * 16 + lm;
        ctx[rg * 512 + cg] = f2bf(oacc[rt][dt][r] * inv0[rt][r]);
      }
}

// ---------------- launch ----------------
extern "C" void kernel_launch(void* const* d_in, const int* in_sizes, int n_in,
                              void* d_out, int out_size, void* d_ws, size_t ws_size,
                              hipStream_t stream) {
  const float* q_in = (const float*)d_in[0];
  const float* k_in = (const float*)d_in[1];
  const float* v_in = (const float*)d_in[2];
  const float* Wq = (const float*)d_in[3];
  const float* bq = (const float*)d_in[4];
  const float* Wk = (const float*)d_in[5];
  const float* bk = (const float*)d_in[6];
  const float* Wv = (const float*)d_in[7];
  const float* bv = (const float*)d_in[8];
  const float* Wo = (const float*)d_in[9];
  const float* bo = (const float*)d_in[10];

  char* ws = (char*)d_ws;
  const size_t SZ = (size_t)16384 * 512 * 2;
  unsigned short* qb = (unsigned short*)(ws + 3 * SZ);
  unsigned short* kb = (unsigned short*)(ws + 4 * SZ);
  unsigned short* wq_b = (unsigned short*)(ws + 5 * SZ);
  unsigned short* wk_b = wq_b + 262144;
  unsigned short* wv_b = wk_b + 262144;
  unsigned short* wo_b = wv_b + 262144;
  unsigned short* vtb = (unsigned short*)d_out;  // vT in d_out (dead before gemm_out)
  unsigned short* ctx = (unsigned short*)ws;     // ws[0] free

  convert_w<<<dim3(128, 1, 4), 256, 0, stream>>>(Wq, Wk, Wv, Wo, wq_b, wk_b, wv_b, wo_b);
  gemm_qkv<<<dim3(512, 1, 3), 256, 0, stream>>>(q_in, k_in, v_in, wq_b, wk_b, wv_b,
                                                bq, bk, bv, qb, kb, vtb);
  attn_kernel<<<1024, 256, 0, stream>>>(qb, kb, vtb, ctx);
  gemm_out<<<dim3(512, 1), 256, 0, stream>>>(ctx, wo_b, bo, (float*)d_out);
}